// Round 7
// baseline (225.585 us; speedup 1.0000x reference)
//
#include <hip/hip_runtime.h>

#define N_NODES 10000
#define HB 64          // histogram chunks
#define NMID 40        // (N_NODES+255)/256

typedef unsigned int uint;
typedef unsigned short ushort;
typedef __attribute__((ext_vector_type(8))) short bf16x8;
typedef __attribute__((ext_vector_type(4))) float f32x4;

__device__ __forceinline__ ushort f2bf(float f) {
    uint b = __float_as_uint(f);
    b += 0x7fffu + ((b >> 16) & 1u);
    return (ushort)(b >> 16);
}

// ---------------- fused prologue ----------------
// blocks [0, HB)            : per-chunk LDS histogram + local rank (CSR critical path, first)
// blocks [HB, HB+CAST_B)    : xb = bf16(x)   (block HB also zeroes aggv+offsdone flags)
// blocks [HB+CAST_B, ...)   : W1T/W2T transpose-cast
#define CAST_B 1250   // N_NODES*128/4 / 256
#define TCAST_B 512   // 2*65536 / 256

__global__ __launch_bounds__(256) void prep_kernel(const float* __restrict__ x,
                                                   const float* __restrict__ W1l,
                                                   const float* __restrict__ W1r,
                                                   const float* __restrict__ W2l,
                                                   const float* __restrict__ W2r,
                                                   const int* __restrict__ dst, int E, int chunk,
                                                   int* __restrict__ chunk_hist,
                                                   ushort* __restrict__ lrank,
                                                   ushort* __restrict__ xb,
                                                   ushort* __restrict__ W1T,
                                                   ushort* __restrict__ W2T,
                                                   int* __restrict__ aggv) {
    __shared__ int hist[N_NODES];   // 40 KB
    int b = blockIdx.x;
    int t = threadIdx.x;
    if (b < HB) {
        for (int i = t; i < N_NODES; i += 256) hist[i] = 0;
        __syncthreads();
        int e0 = b * chunk;
        int e1 = e0 + chunk; if (e1 > E) e1 = E;
        for (int e = e0 + t; e < e1; e += 256) {
            int d = dst[e];
            lrank[e] = (ushort)atomicAdd(&hist[d], 1);
        }
        __syncthreads();
        for (int i = t; i < N_NODES; i += 256) chunk_hist[b * N_NODES + i] = hist[i];
    } else if (b < HB + CAST_B) {
        if (b == HB && t < 128) aggv[t] = 0;   // zero aggv[64] + offsdone[64]
        int i = (b - HB) * 256 + t;
        float4 v = ((const float4*)x)[i];
        ushort4 o;
        o.x = f2bf(v.x); o.y = f2bf(v.y); o.z = f2bf(v.z); o.w = f2bf(v.w);
        ((ushort4*)xb)[i] = o;
    } else {
        int id = (b - HB - CAST_B) * 256 + t;    // 0..131071
        int z = id >> 16;
        int k = (id >> 8) & 255;
        int c = id & 255;
        if (z == 0) {
            // W1T[c][k] = k<128 ? W1l[k][c] : W1r[k-128][c]
            float v = (k < 128) ? W1l[k * 256 + c] : W1r[(k - 128) * 256 + c];
            W1T[c * 256 + k] = f2bf(v);
        } else {
            // W2T[c][k] = c<128 ? W2l[k][c] : W2r[k][c-128]
            float v = (c < 128) ? W2l[k * 128 + c] : W2r[k * 128 + (c - 128)];
            W2T[c * 256 + k] = f2bf(v);
        }
    }
}

// ---------------- CSR finish: mid (colsum+lookback-scan+offs) THEN scatter, one kernel ----------------
// blocks [0, NMID)      : csr_mid work; release-store offsdone[b] when offs written
// blocks [NMID, ...)    : prefetch edge data -> acquire-spin on 40 flags -> scatter
// Co-residency by capacity: 665 blocks, launch_bounds(256,4) -> >=1024 slots -> no deadlock.
__global__ __launch_bounds__(256, 4) void csr_finish(const int* __restrict__ src,
                                                     const int* __restrict__ dst,
                                                     const ushort* __restrict__ lrank,
                                                     int* __restrict__ ch,
                                                     int* __restrict__ row_ptr,
                                                     int* __restrict__ aggv,
                                                     int* __restrict__ offsdone,
                                                     int E, int chunk,
                                                     ushort* __restrict__ csr) {
    int b = blockIdx.x, t = threadIdx.x;
    if (b < NMID) {
        int n = b * 256 + t;
        bool ok = n < N_NODES;
        int s = 0;
        if (ok) {
#pragma unroll 8
            for (int c = 0; c < HB; ++c) s += ch[c * N_NODES + n];
        }
        // block-wide inclusive scan
        int lane = t & 63, wid = t >> 6;
        int incl = s;
#pragma unroll
        for (int off = 1; off < 64; off <<= 1) {
            int y = __shfl_up(incl, off);
            if (lane >= off) incl += y;
        }
        __shared__ int wsum[4];
        __shared__ int sbase;
        if (lane == 63) wsum[wid] = incl;
        __syncthreads();
        int tot = wsum[0] + wsum[1] + wsum[2] + wsum[3];
        int wbase = 0;
#pragma unroll
        for (int w = 0; w < 4; ++w)
            if (w < wid) wbase += wsum[w];
        incl += wbase;
        // publish aggregate FIRST (no circular wait), then look back
        if (t == 0)
            __hip_atomic_store(&aggv[b], tot + 1, __ATOMIC_RELEASE, __HIP_MEMORY_SCOPE_AGENT);
        if (t < 64) {
            int v = 0;
            if (t < b) {
                do {
                    v = __hip_atomic_load(&aggv[t], __ATOMIC_ACQUIRE, __HIP_MEMORY_SCOPE_AGENT);
                } while (v == 0);
                --v;
            }
#pragma unroll
            for (int m = 1; m < 64; m <<= 1) v += __shfl_xor(v, m);
            if (t == 0) sbase = v;
        }
        __syncthreads();
        int base = sbase;
        if (b == 0 && t == 0) row_ptr[0] = 0;
        if (ok) {
            row_ptr[n + 1] = base + incl;
            int run = base + incl - s;      // exclusive prefix = global start of node n
#pragma unroll 8
            for (int c = 0; c < HB; ++c) {
                int v = ch[c * N_NODES + n];
                ch[c * N_NODES + n] = run;
                run += v;
            }
        }
        __syncthreads();   // compiler drains all offs writes (vmcnt 0) before barrier
        if (t == 0)
            __hip_atomic_store(&offsdone[b], 1, __ATOMIC_RELEASE, __HIP_MEMORY_SCOPE_AGENT);
    } else {
        int g = (b - NMID) * 256 + t;
        int e = g * 4;
        bool full = (e + 3 < E);
        int4 d, sv; ushort4 r;
        if (full) {   // prefetch edge data into registers; latency hides under the spin
            d = *(const int4*)&dst[e];
            sv = *(const int4*)&src[e];
            r = *(const ushort4*)&lrank[e];
        }
        if (t < NMID) {
            while (__hip_atomic_load(&offsdone[t], __ATOMIC_ACQUIRE,
                                     __HIP_MEMORY_SCOPE_AGENT) == 0)
                __builtin_amdgcn_s_sleep(8);
        }
        __syncthreads();
        __builtin_amdgcn_fence(__ATOMIC_ACQUIRE, "agent");
        if (full) {
            int bb = e / chunk;             // chunk multiple of 4 -> uniform for the 4-group
            const int* ob = ch + bb * N_NODES;
            csr[ob[d.x] + r.x] = (ushort)sv.x;
            csr[ob[d.y] + r.y] = (ushort)sv.y;
            csr[ob[d.z] + r.z] = (ushort)sv.z;
            csr[ob[d.w] + r.w] = (ushort)sv.w;
        } else {
            for (; e < E; ++e)
                csr[ch[(e / chunk) * N_NODES + dst[e]] + lrank[e]] = (ushort)src[e];
        }
    }
}

// ---------------- Aggregation (gather mean), bf16 feat, 128 channels ----------------
// MODE 0: write packed bf16 mean -> outb ; MODE 1: out f32 += mean
// 8 edges in flight per iteration (avg degree 64 -> 8 full iterations).
template <int MODE>
__global__ __launch_bounds__(256) void agg_kernel(const ushort* __restrict__ feat,
                                                  const int* __restrict__ row_ptr,
                                                  const ushort* __restrict__ csr,
                                                  uint* __restrict__ outb,
                                                  float* __restrict__ out) {
    int wave = threadIdx.x >> 6;
    int lane = threadIdx.x & 63;
    int n = blockIdx.x * 4 + wave;
    if (n >= N_NODES) return;
    int beg = row_ptr[n], end = row_ptr[n + 1];
    const uint* f = (const uint*)feat;
    float ax0 = 0, ay0 = 0, ax1 = 0, ay1 = 0, ax2 = 0, ay2 = 0, ax3 = 0, ay3 = 0;
    int i = beg;
    for (; i + 8 <= end; i += 8) {
        int s0 = csr[i + 0];
        int s1 = csr[i + 1];
        int s2 = csr[i + 2];
        int s3 = csr[i + 3];
        int s4 = csr[i + 4];
        int s5 = csr[i + 5];
        int s6 = csr[i + 6];
        int s7 = csr[i + 7];
        uint u0 = f[s0 * 64 + lane];
        uint u1 = f[s1 * 64 + lane];
        uint u2 = f[s2 * 64 + lane];
        uint u3 = f[s3 * 64 + lane];
        uint u4 = f[s4 * 64 + lane];
        uint u5 = f[s5 * 64 + lane];
        uint u6 = f[s6 * 64 + lane];
        uint u7 = f[s7 * 64 + lane];
        ax0 += __uint_as_float(u0 << 16); ay0 += __uint_as_float(u0 & 0xffff0000u);
        ax1 += __uint_as_float(u1 << 16); ay1 += __uint_as_float(u1 & 0xffff0000u);
        ax2 += __uint_as_float(u2 << 16); ay2 += __uint_as_float(u2 & 0xffff0000u);
        ax3 += __uint_as_float(u3 << 16); ay3 += __uint_as_float(u3 & 0xffff0000u);
        ax0 += __uint_as_float(u4 << 16); ay0 += __uint_as_float(u4 & 0xffff0000u);
        ax1 += __uint_as_float(u5 << 16); ay1 += __uint_as_float(u5 & 0xffff0000u);
        ax2 += __uint_as_float(u6 << 16); ay2 += __uint_as_float(u6 & 0xffff0000u);
        ax3 += __uint_as_float(u7 << 16); ay3 += __uint_as_float(u7 & 0xffff0000u);
    }
    for (; i + 4 <= end; i += 4) {
        int s0 = csr[i + 0];
        int s1 = csr[i + 1];
        int s2 = csr[i + 2];
        int s3 = csr[i + 3];
        uint u0 = f[s0 * 64 + lane];
        uint u1 = f[s1 * 64 + lane];
        uint u2 = f[s2 * 64 + lane];
        uint u3 = f[s3 * 64 + lane];
        ax0 += __uint_as_float(u0 << 16); ay0 += __uint_as_float(u0 & 0xffff0000u);
        ax1 += __uint_as_float(u1 << 16); ay1 += __uint_as_float(u1 & 0xffff0000u);
        ax2 += __uint_as_float(u2 << 16); ay2 += __uint_as_float(u2 & 0xffff0000u);
        ax3 += __uint_as_float(u3 << 16); ay3 += __uint_as_float(u3 & 0xffff0000u);
    }
    for (; i < end; ++i) {
        int s = csr[i];
        uint u = f[s * 64 + lane];
        ax0 += __uint_as_float(u << 16); ay0 += __uint_as_float(u & 0xffff0000u);
    }
    float deg = (float)(end - beg);
    float inv = deg > 0.f ? 1.0f / deg : 0.0f;
    float sx = ((ax0 + ax1) + (ax2 + ax3)) * inv;
    float sy = ((ay0 + ay1) + (ay2 + ay3)) * inv;
    if (MODE == 0) {
        outb[n * 64 + lane] = (uint)f2bf(sx) | ((uint)f2bf(sy) << 16);
    } else {
        float2* o = (float2*)&out[n * 128 + lane * 2];
        float2 prev = *o;
        prev.x += sx; prev.y += sy;
        *o = prev;
    }
}

// ---------------- fused MFMA GEMM: 16-row panels, 4 waves split columns ----------------
// grid = 625 blocks (10000 = 625*16, no bounds checks). Block owns rows r0..r0+15.
// Wave w owns cols w*64..w*64+63 for BOTH gemms.
// gemm1: h[16][256] = relu([mean1|x] @ W1T^T + b1) -> LDS (stride 264 kills bank conflicts)
// gemm2: vcols 0-127 -> t = bf16(h@W2l) ; vcols 128-255 -> out = h@W2r + b2
__global__ __launch_bounds__(256) void gemm_fused(const ushort* __restrict__ m1b,
                                                  const ushort* __restrict__ xb,
                                                  const ushort* __restrict__ W1T,
                                                  const float* __restrict__ b1,
                                                  const ushort* __restrict__ W2T,
                                                  const float* __restrict__ b2,
                                                  ushort* __restrict__ t,
                                                  float* __restrict__ out) {
    __shared__ ushort hsh[16 * 264];   // 8.25 KB
    int w = threadIdx.x >> 6, lane = threadIdx.x & 63;
    int lr = lane & 15, lg = lane >> 4;
    int r0 = blockIdx.x * 16;
    int row = r0 + lr;
    int c0 = w * 64;

    // A fragments: rows r0..r0+15 (same for all 4 waves; L1 broadcast)
    bf16x8 afr[8];
#pragma unroll
    for (int ks = 0; ks < 8; ++ks) {
        int k0 = ks * 32;
        const ushort* Ab = (k0 < 128) ? (m1b + row * 128 + k0) : (xb + row * 128 + (k0 - 128));
        afr[ks] = *(const bf16x8*)(Ab + lg * 8);
    }

    // ---- gemm1: 16 rows x 64 cols per wave, epilogue to LDS ----
    {
        f32x4 acc[4] = {};
#pragma unroll
        for (int ks = 0; ks < 8; ++ks) {
            int k0 = ks * 32;
#pragma unroll
            for (int cg = 0; cg < 4; ++cg) {
                int col = c0 + cg * 16 + lr;
                bf16x8 b = *(const bf16x8*)(W1T + col * 256 + k0 + lg * 8);
                acc[cg] = __builtin_amdgcn_mfma_f32_16x16x32_bf16(afr[ks], b, acc[cg], 0, 0, 0);
            }
        }
#pragma unroll
        for (int cg = 0; cg < 4; ++cg) {
            int col = c0 + cg * 16 + lr;
            float bias = b1[col];
#pragma unroll
            for (int i = 0; i < 4; ++i) {
                float v = acc[cg][i] + bias;
                v = v > 0.f ? v : 0.f;
                hsh[(lg * 4 + i) * 264 + col] = f2bf(v);
            }
        }
    }
    __syncthreads();

    // ---- gemm2 A fragments from LDS (rows lr, all 256 k) ----
    bf16x8 afr2[8];
#pragma unroll
    for (int ks = 0; ks < 8; ++ks)
        afr2[ks] = *(const bf16x8*)&hsh[lr * 264 + ks * 32 + lg * 8];

    // ---- gemm2: same 16 rows, vcols c0..c0+63 ----
    {
        f32x4 acc[4] = {};
#pragma unroll
        for (int ks = 0; ks < 8; ++ks) {
            int k0 = ks * 32;
#pragma unroll
            for (int cg = 0; cg < 4; ++cg) {
                int col = c0 + cg * 16 + lr;
                bf16x8 b = *(const bf16x8*)(W2T + col * 256 + k0 + lg * 8);
                acc[cg] = __builtin_amdgcn_mfma_f32_16x16x32_bf16(afr2[ks], b, acc[cg], 0, 0, 0);
            }
        }
#pragma unroll
        for (int cg = 0; cg < 4; ++cg) {
            int col = c0 + cg * 16 + lr;
            if (col < 128) {
#pragma unroll
                for (int i = 0; i < 4; ++i)
                    t[(r0 + lg * 4 + i) * 128 + col] = f2bf(acc[cg][i]);
            } else {
                int oc = col - 128;
                float bias = b2[oc];
#pragma unroll
                for (int i = 0; i < 4; ++i)
                    out[(r0 + lg * 4 + i) * 128 + oc] = acc[cg][i] + bias;
            }
        }
    }
}

// ---------------- launch ----------------

extern "C" void kernel_launch(void* const* d_in, const int* in_sizes, int n_in,
                              void* d_out, int out_size, void* d_ws, size_t ws_size,
                              hipStream_t stream) {
    const float* x   = (const float*)d_in[0];
    const int* edge  = (const int*)d_in[1];
    const float* W1l = (const float*)d_in[2];
    const float* W1r = (const float*)d_in[3];
    const float* b1  = (const float*)d_in[4];
    const float* W2l = (const float*)d_in[5];
    const float* W2r = (const float*)d_in[6];
    const float* b2  = (const float*)d_in[7];
    float* out = (float*)d_out;

    int E = in_sizes[1] / 2;
    const int* src = edge;
    const int* dst = edge + E;
    int chunk = (((E + HB - 1) / HB) + 3) & ~3;   // chunk multiple of 4

    // workspace layout
    ushort* m1b  = (ushort*)d_ws;                         // [N,128] bf16 mean1 (later aliased by t)
    ushort* hb   = m1b + (size_t)N_NODES * 128;           // [N,256] bf16 (layout spacer)
    ushort* xb   = hb + (size_t)N_NODES * 256;            // [N,128] bf16
    ushort* W1T  = xb + (size_t)N_NODES * 128;            // [256][256] bf16
    ushort* W2T  = W1T + 256 * 256;                       // [256][256] bf16
    ushort* csr  = W2T + 256 * 256;                       // [E]
    ushort* lrank= csr + E;                               // [E]
    int* chist   = (int*)(lrank + E);                     // [HB][N]
    int* row_ptr = chist + HB * N_NODES;                  // [N+1]
    int* aggv    = row_ptr + (N_NODES + 1);               // [64] lookback aggregates
    int* offsdone= aggv + 64;                             // [64] mid-done flags (40 used)
    ushort* tb   = m1b;                                   // t aliases mean1 (row-panel exclusive)

    // fused prologue: hist (first, CSR critical path) + cast x (+ zero flags) + tcast weights
    prep_kernel<<<HB + CAST_B + TCAST_B, 256, 0, stream>>>(x, W1l, W1r, W2l, W2r,
                                                           dst, E, chunk, chist, lrank,
                                                           xb, W1T, W2T, aggv);

    // CSR finish: mid (lookback scan + offs) -> flag -> scatter, one kernel
    int nsc = (E / 4 + 255) / 256;
    csr_finish<<<NMID + nsc, 256, 0, stream>>>(src, dst, lrank, chist, row_ptr,
                                               aggv, offsdone, E, chunk, csr);

    // layer 1 aggregation
    agg_kernel<0><<<(N_NODES + 3) / 4, 256, 0, stream>>>(xb, row_ptr, csr, (uint*)m1b, nullptr);

    // fused gemm1+gemm2, 16-row panels (h stays in LDS; t = bf16(h@W2l); out = h@W2r + b2)
    gemm_fused<<<N_NODES / 16, 256, 0, stream>>>(m1b, xb, W1T, b1, W2T, b2, tb, out);

    // layer 2 aggregation: out += segment_mean(t)
    agg_kernel<1><<<(N_NODES + 3) / 4, 256, 0, stream>>>(tb, row_ptr, csr, nullptr, out);
}

// Round 8
// 99.381 us; speedup vs baseline: 2.2699x; 2.2699x over previous
//
#include <hip/hip_runtime.h>

#define N_NODES 10000
#define HB 128         // histogram chunks (halved per-block hist work vs 64)

typedef unsigned int uint;
typedef unsigned short ushort;
typedef __attribute__((ext_vector_type(8))) short bf16x8;
typedef __attribute__((ext_vector_type(4))) float f32x4;

__device__ __forceinline__ ushort f2bf(float f) {
    uint b = __float_as_uint(f);
    b += 0x7fffu + ((b >> 16) & 1u);
    return (ushort)(b >> 16);
}

// ---------------- fused prologue ----------------
// blocks [0, HB)            : per-chunk LDS histogram + local rank (CSR critical path, first)
// blocks [HB, HB+CAST_B)    : xb = bf16(x)   (block HB also zeroes aggv flags)
// blocks [HB+CAST_B, ...)   : W1T/W2T transpose-cast
#define CAST_B 1250   // N_NODES*128/4 / 256
#define TCAST_B 512   // 2*65536 / 256

__global__ __launch_bounds__(256) void prep_kernel(const float* __restrict__ x,
                                                   const float* __restrict__ W1l,
                                                   const float* __restrict__ W1r,
                                                   const float* __restrict__ W2l,
                                                   const float* __restrict__ W2r,
                                                   const int* __restrict__ dst, int E, int chunk,
                                                   int* __restrict__ chunk_hist,
                                                   ushort* __restrict__ lrank,
                                                   ushort* __restrict__ xb,
                                                   ushort* __restrict__ W1T,
                                                   ushort* __restrict__ W2T,
                                                   int* __restrict__ aggv) {
    __shared__ int hist[N_NODES];   // 40 KB
    int b = blockIdx.x;
    int t = threadIdx.x;
    if (b < HB) {
        // int4 zero: 2500 int4s
        int4* h4 = (int4*)hist;
        for (int i = t; i < N_NODES / 4; i += 256) h4[i] = make_int4(0, 0, 0, 0);
        __syncthreads();
        int e0 = b * chunk;
        int e1 = e0 + chunk; if (e1 > E) e1 = E;
        for (int e = e0 + t; e < e1; e += 256) {
            int d = dst[e];
            lrank[e] = (ushort)atomicAdd(&hist[d], 1);
        }
        __syncthreads();
        int4* c4 = (int4*)(chunk_hist + b * N_NODES);
        for (int i = t; i < N_NODES / 4; i += 256) c4[i] = h4[i];
    } else if (b < HB + CAST_B) {
        if (b == HB && t < 64) aggv[t] = 0;    // zero lookback flags for csr_mid
        int i = (b - HB) * 256 + t;
        float4 v = ((const float4*)x)[i];
        ushort4 o;
        o.x = f2bf(v.x); o.y = f2bf(v.y); o.z = f2bf(v.z); o.w = f2bf(v.w);
        ((ushort4*)xb)[i] = o;
    } else {
        int id = (b - HB - CAST_B) * 256 + t;    // 0..131071
        int z = id >> 16;
        int k = (id >> 8) & 255;
        int c = id & 255;
        if (z == 0) {
            // W1T[c][k] = k<128 ? W1l[k][c] : W1r[k-128][c]
            float v = (k < 128) ? W1l[k * 256 + c] : W1r[(k - 128) * 256 + c];
            W1T[c * 256 + k] = f2bf(v);
        } else {
            // W2T[c][k] = c<128 ? W2l[k][c] : W2r[k][c-128]
            float v = (c < 128) ? W2l[k * 128 + c] : W2r[k * 128 + (c - 128)];
            W2T[c * 256 + k] = f2bf(v);
        }
    }
}

// ---------------- CSR mid-chain, fused: colsum + scan (decoupled lookback) + offs ----------------
__global__ __launch_bounds__(256) void csr_mid_kernel(int* __restrict__ ch,
                                                      int* __restrict__ row_ptr,
                                                      int* __restrict__ aggv) {
    int b = blockIdx.x, t = threadIdx.x;
    int n = b * 256 + t;
    bool ok = n < N_NODES;
    int s = 0;
    if (ok) {
#pragma unroll 8
        for (int c = 0; c < HB; ++c) s += ch[c * N_NODES + n];
    }
    // block-wide inclusive scan
    int lane = t & 63, wid = t >> 6;
    int incl = s;
#pragma unroll
    for (int off = 1; off < 64; off <<= 1) {
        int y = __shfl_up(incl, off);
        if (lane >= off) incl += y;
    }
    __shared__ int wsum[4];
    __shared__ int sbase;
    if (lane == 63) wsum[wid] = incl;
    __syncthreads();
    int tot = wsum[0] + wsum[1] + wsum[2] + wsum[3];
    int wbase = 0;
#pragma unroll
    for (int w = 0; w < 4; ++w)
        if (w < wid) wbase += wsum[w];
    incl += wbase;
    // publish aggregate FIRST (no circular wait), then look back
    if (t == 0)
        __hip_atomic_store(&aggv[b], tot + 1, __ATOMIC_RELEASE, __HIP_MEMORY_SCOPE_AGENT);
    if (t < 64) {
        int v = 0;
        if (t < b) {
            do {
                v = __hip_atomic_load(&aggv[t], __ATOMIC_ACQUIRE, __HIP_MEMORY_SCOPE_AGENT);
            } while (v == 0);
            --v;
        }
#pragma unroll
        for (int m = 1; m < 64; m <<= 1) v += __shfl_xor(v, m);
        if (t == 0) sbase = v;
    }
    __syncthreads();
    int base = sbase;
    if (b == 0 && t == 0) row_ptr[0] = 0;
    if (ok) {
        row_ptr[n + 1] = base + incl;
        int run = base + incl - s;      // exclusive prefix = global start of node n
#pragma unroll 8
        for (int c = 0; c < HB; ++c) {
            int v = ch[c * N_NODES + n];
            ch[c * N_NODES + n] = run;
            run += v;
        }
    }
}

// ---------------- atomic-free scatter ----------------
__global__ __launch_bounds__(256) void scatter_kernel(const int* __restrict__ src,
                                                      const int* __restrict__ dst,
                                                      const ushort* __restrict__ lrank,
                                                      const int* __restrict__ off,
                                                      int E, int chunk,
                                                      ushort* __restrict__ csr) {
    int g = blockIdx.x * blockDim.x + threadIdx.x;
    int e = g * 4;
    if (e + 3 < E) {
        int b = e / chunk;                    // chunk is multiple of 4, so uniform for the 4-group
        const int* ob = off + b * N_NODES;
        int4 d = *(const int4*)&dst[e];
        int4 s = *(const int4*)&src[e];
        ushort4 r = *(const ushort4*)&lrank[e];
        csr[ob[d.x] + r.x] = (ushort)s.x;
        csr[ob[d.y] + r.y] = (ushort)s.y;
        csr[ob[d.z] + r.z] = (ushort)s.z;
        csr[ob[d.w] + r.w] = (ushort)s.w;
    } else {
        for (; e < E; ++e)
            csr[off[(e / chunk) * N_NODES + dst[e]] + lrank[e]] = (ushort)src[e];
    }
}

// ---------------- Aggregation (gather mean), bf16 feat, 128 channels ----------------
// MODE 0: write packed bf16 mean -> outb ; MODE 1: out f32 += mean
// 8 edges in flight per iteration (avg degree 64 -> 8 full iterations).
template <int MODE>
__global__ __launch_bounds__(256) void agg_kernel(const ushort* __restrict__ feat,
                                                  const int* __restrict__ row_ptr,
                                                  const ushort* __restrict__ csr,
                                                  uint* __restrict__ outb,
                                                  float* __restrict__ out) {
    int wave = threadIdx.x >> 6;
    int lane = threadIdx.x & 63;
    int n = blockIdx.x * 4 + wave;
    if (n >= N_NODES) return;
    int beg = row_ptr[n], end = row_ptr[n + 1];
    const uint* f = (const uint*)feat;
    float ax0 = 0, ay0 = 0, ax1 = 0, ay1 = 0, ax2 = 0, ay2 = 0, ax3 = 0, ay3 = 0;
    int i = beg;
    for (; i + 8 <= end; i += 8) {
        int s0 = csr[i + 0];
        int s1 = csr[i + 1];
        int s2 = csr[i + 2];
        int s3 = csr[i + 3];
        int s4 = csr[i + 4];
        int s5 = csr[i + 5];
        int s6 = csr[i + 6];
        int s7 = csr[i + 7];
        uint u0 = f[s0 * 64 + lane];
        uint u1 = f[s1 * 64 + lane];
        uint u2 = f[s2 * 64 + lane];
        uint u3 = f[s3 * 64 + lane];
        uint u4 = f[s4 * 64 + lane];
        uint u5 = f[s5 * 64 + lane];
        uint u6 = f[s6 * 64 + lane];
        uint u7 = f[s7 * 64 + lane];
        ax0 += __uint_as_float(u0 << 16); ay0 += __uint_as_float(u0 & 0xffff0000u);
        ax1 += __uint_as_float(u1 << 16); ay1 += __uint_as_float(u1 & 0xffff0000u);
        ax2 += __uint_as_float(u2 << 16); ay2 += __uint_as_float(u2 & 0xffff0000u);
        ax3 += __uint_as_float(u3 << 16); ay3 += __uint_as_float(u3 & 0xffff0000u);
        ax0 += __uint_as_float(u4 << 16); ay0 += __uint_as_float(u4 & 0xffff0000u);
        ax1 += __uint_as_float(u5 << 16); ay1 += __uint_as_float(u5 & 0xffff0000u);
        ax2 += __uint_as_float(u6 << 16); ay2 += __uint_as_float(u6 & 0xffff0000u);
        ax3 += __uint_as_float(u7 << 16); ay3 += __uint_as_float(u7 & 0xffff0000u);
    }
    for (; i + 4 <= end; i += 4) {
        int s0 = csr[i + 0];
        int s1 = csr[i + 1];
        int s2 = csr[i + 2];
        int s3 = csr[i + 3];
        uint u0 = f[s0 * 64 + lane];
        uint u1 = f[s1 * 64 + lane];
        uint u2 = f[s2 * 64 + lane];
        uint u3 = f[s3 * 64 + lane];
        ax0 += __uint_as_float(u0 << 16); ay0 += __uint_as_float(u0 & 0xffff0000u);
        ax1 += __uint_as_float(u1 << 16); ay1 += __uint_as_float(u1 & 0xffff0000u);
        ax2 += __uint_as_float(u2 << 16); ay2 += __uint_as_float(u2 & 0xffff0000u);
        ax3 += __uint_as_float(u3 << 16); ay3 += __uint_as_float(u3 & 0xffff0000u);
    }
    for (; i < end; ++i) {
        int s = csr[i];
        uint u = f[s * 64 + lane];
        ax0 += __uint_as_float(u << 16); ay0 += __uint_as_float(u & 0xffff0000u);
    }
    float deg = (float)(end - beg);
    float inv = deg > 0.f ? 1.0f / deg : 0.0f;
    float sx = ((ax0 + ax1) + (ax2 + ax3)) * inv;
    float sy = ((ay0 + ay1) + (ay2 + ay3)) * inv;
    if (MODE == 0) {
        outb[n * 64 + lane] = (uint)f2bf(sx) | ((uint)f2bf(sy) << 16);
    } else {
        float2* o = (float2*)&out[n * 128 + lane * 2];
        float2 prev = *o;
        prev.x += sx; prev.y += sy;
        *o = prev;
    }
}

// ---------------- fused MFMA GEMM: 16-row panels, 4 waves split columns ----------------
// grid = 625 blocks (10000 = 625*16, no bounds checks). Block owns rows r0..r0+15.
// Wave w owns cols w*64..w*64+63 for BOTH gemms.
// gemm1: h[16][256] = relu([mean1|x] @ W1T^T + b1) -> LDS (stride 264 kills bank conflicts)
// gemm2: vcols 0-127 -> t = bf16(h@W2l) ; vcols 128-255 -> out = h@W2r + b2
__global__ __launch_bounds__(256) void gemm_fused(const ushort* __restrict__ m1b,
                                                  const ushort* __restrict__ xb,
                                                  const ushort* __restrict__ W1T,
                                                  const float* __restrict__ b1,
                                                  const ushort* __restrict__ W2T,
                                                  const float* __restrict__ b2,
                                                  ushort* __restrict__ t,
                                                  float* __restrict__ out) {
    __shared__ ushort hsh[16 * 264];   // 8.25 KB
    int w = threadIdx.x >> 6, lane = threadIdx.x & 63;
    int lr = lane & 15, lg = lane >> 4;
    int r0 = blockIdx.x * 16;
    int row = r0 + lr;
    int c0 = w * 64;

    // A fragments: rows r0..r0+15 (same for all 4 waves; L1 broadcast)
    bf16x8 afr[8];
#pragma unroll
    for (int ks = 0; ks < 8; ++ks) {
        int k0 = ks * 32;
        const ushort* Ab = (k0 < 128) ? (m1b + row * 128 + k0) : (xb + row * 128 + (k0 - 128));
        afr[ks] = *(const bf16x8*)(Ab + lg * 8);
    }

    // ---- gemm1: 16 rows x 64 cols per wave, epilogue to LDS ----
    {
        f32x4 acc[4] = {};
#pragma unroll
        for (int ks = 0; ks < 8; ++ks) {
            int k0 = ks * 32;
#pragma unroll
            for (int cg = 0; cg < 4; ++cg) {
                int col = c0 + cg * 16 + lr;
                bf16x8 b = *(const bf16x8*)(W1T + col * 256 + k0 + lg * 8);
                acc[cg] = __builtin_amdgcn_mfma_f32_16x16x32_bf16(afr[ks], b, acc[cg], 0, 0, 0);
            }
        }
#pragma unroll
        for (int cg = 0; cg < 4; ++cg) {
            int col = c0 + cg * 16 + lr;
            float bias = b1[col];
#pragma unroll
            for (int i = 0; i < 4; ++i) {
                float v = acc[cg][i] + bias;
                v = v > 0.f ? v : 0.f;
                hsh[(lg * 4 + i) * 264 + col] = f2bf(v);
            }
        }
    }
    __syncthreads();

    // ---- gemm2 A fragments from LDS (rows lr, all 256 k) ----
    bf16x8 afr2[8];
#pragma unroll
    for (int ks = 0; ks < 8; ++ks)
        afr2[ks] = *(const bf16x8*)&hsh[lr * 264 + ks * 32 + lg * 8];

    // ---- gemm2: same 16 rows, vcols c0..c0+63 ----
    {
        f32x4 acc[4] = {};
#pragma unroll
        for (int ks = 0; ks < 8; ++ks) {
            int k0 = ks * 32;
#pragma unroll
            for (int cg = 0; cg < 4; ++cg) {
                int col = c0 + cg * 16 + lr;
                bf16x8 b = *(const bf16x8*)(W2T + col * 256 + k0 + lg * 8);
                acc[cg] = __builtin_amdgcn_mfma_f32_16x16x32_bf16(afr2[ks], b, acc[cg], 0, 0, 0);
            }
        }
#pragma unroll
        for (int cg = 0; cg < 4; ++cg) {
            int col = c0 + cg * 16 + lr;
            if (col < 128) {
#pragma unroll
                for (int i = 0; i < 4; ++i)
                    t[(r0 + lg * 4 + i) * 128 + col] = f2bf(acc[cg][i]);
            } else {
                int oc = col - 128;
                float bias = b2[oc];
#pragma unroll
                for (int i = 0; i < 4; ++i)
                    out[(r0 + lg * 4 + i) * 128 + oc] = acc[cg][i] + bias;
            }
        }
    }
}

// ---------------- launch ----------------

extern "C" void kernel_launch(void* const* d_in, const int* in_sizes, int n_in,
                              void* d_out, int out_size, void* d_ws, size_t ws_size,
                              hipStream_t stream) {
    const float* x   = (const float*)d_in[0];
    const int* edge  = (const int*)d_in[1];
    const float* W1l = (const float*)d_in[2];
    const float* W1r = (const float*)d_in[3];
    const float* b1  = (const float*)d_in[4];
    const float* W2l = (const float*)d_in[5];
    const float* W2r = (const float*)d_in[6];
    const float* b2  = (const float*)d_in[7];
    float* out = (float*)d_out;

    int E = in_sizes[1] / 2;
    const int* src = edge;
    const int* dst = edge + E;
    int chunk = (((E + HB - 1) / HB) + 3) & ~3;   // chunk multiple of 4

    // workspace layout
    ushort* m1b  = (ushort*)d_ws;                         // [N,128] bf16 mean1 (later aliased by t)
    ushort* hb   = m1b + (size_t)N_NODES * 128;           // [N,256] bf16 (layout spacer)
    ushort* xb   = hb + (size_t)N_NODES * 256;            // [N,128] bf16
    ushort* W1T  = xb + (size_t)N_NODES * 128;            // [256][256] bf16
    ushort* W2T  = W1T + 256 * 256;                       // [256][256] bf16
    ushort* csr  = W2T + 256 * 256;                       // [E]
    ushort* lrank= csr + E;                               // [E]
    int* chist   = (int*)(lrank + E);                     // [HB][N]
    int* row_ptr = chist + HB * N_NODES;                  // [N+1]
    int* aggv    = row_ptr + (N_NODES + 1);               // [64] lookback aggregates
    ushort* tb   = m1b;                                   // t aliases mean1 (row-panel exclusive)

    // fused prologue: hist (first, CSR critical path) + cast x (+ zero aggv) + tcast weights
    prep_kernel<<<HB + CAST_B + TCAST_B, 256, 0, stream>>>(x, W1l, W1r, W2l, W2r,
                                                           dst, E, chunk, chist, lrank,
                                                           xb, W1T, W2T, aggv);

    // CSR mid-chain: one kernel (decoupled lookback scan)
    csr_mid_kernel<<<(N_NODES + 255) / 256, 256, 0, stream>>>(chist, row_ptr, aggv);

    // scatter (atomic-free)
    scatter_kernel<<<(E / 4 + 255) / 256, 256, 0, stream>>>(src, dst, lrank, chist, E, chunk, csr);

    // layer 1 aggregation
    agg_kernel<0><<<(N_NODES + 3) / 4, 256, 0, stream>>>(xb, row_ptr, csr, (uint*)m1b, nullptr);

    // fused gemm1+gemm2, 16-row panels (h stays in LDS; t = bf16(h@W2l); out = h@W2r + b2)
    gemm_fused<<<N_NODES / 16, 256, 0, stream>>>(m1b, xb, W1T, b1, W2T, b2, tb, out);

    // layer 2 aggregation: out += segment_mean(t)
    agg_kernel<1><<<(N_NODES + 3) / 4, 256, 0, stream>>>(tb, row_ptr, csr, nullptr, out);
}